// Round 1
// baseline (135.394 us; speedup 1.0000x reference)
//
#include <hip/hip_runtime.h>

#define BB 2
#define NN 512
#define MM 512
#define DD 128
#define HH 256

// ---------------------------------------------------------------------------
// Kernel A: hx[b,n,h] = X[b,n,:]@W1x[:,h] + b1[h]   (b1 folded into hx)
//           hy[b,m,h] = Y[b,m,:]@W1y[:,h]
// 8-row register tile per block so W1 is read once per 8 rows.
// grid = 256 (128 X-tiles + 128 Y-tiles), block = 256 (thread = h)
// ---------------------------------------------------------------------------
__global__ __launch_bounds__(256) void k_inproj(
    const float* __restrict__ X, const float* __restrict__ Y,
    const float* __restrict__ W1x, const float* __restrict__ W1y,
    const float* __restrict__ b1,
    float* __restrict__ hx, float* __restrict__ hy)
{
    __shared__ float sr[DD][8];   // transposed row tile for float4 broadcast
    int blk = blockIdx.x;
    bool isX = blk < 128;
    const float* src = isX ? X : Y;
    const float* W   = isX ? W1x : W1y;
    float* dst       = isX ? hx : hy;
    int row0 = (isX ? blk : blk - 128) * 8;
    int t = threadIdx.x;

    for (int k = 0; k < 4; ++k) {
        int idx = t + k * 256;             // 0..1023 over (r,d), d fastest
        int r = idx >> 7, d = idx & 127;
        sr[d][r] = src[(row0 + r) * DD + d];
    }
    __syncthreads();

    float bias = isX ? b1[t] : 0.0f;
    float acc[8];
#pragma unroll
    for (int i = 0; i < 8; ++i) acc[i] = bias;

    for (int d = 0; d < DD; ++d) {
        float w = W[d * HH + t];           // coalesced, L2-resident
        float4 a0 = *(const float4*)&sr[d][0];
        float4 a1 = *(const float4*)&sr[d][4];
        acc[0] = fmaf(a0.x, w, acc[0]);
        acc[1] = fmaf(a0.y, w, acc[1]);
        acc[2] = fmaf(a0.z, w, acc[2]);
        acc[3] = fmaf(a0.w, w, acc[3]);
        acc[4] = fmaf(a1.x, w, acc[4]);
        acc[5] = fmaf(a1.y, w, acc[5]);
        acc[6] = fmaf(a1.z, w, acc[6]);
        acc[7] = fmaf(a1.w, w, acc[7]);
    }
#pragma unroll
    for (int i = 0; i < 8; ++i) dst[(row0 + i) * HH + t] = acc[i];
}

// ---------------------------------------------------------------------------
// Kernel B: Spart[ms][b,n,h] = sum_{m in half ms} mask[b,n,m]*relu(hx+hy)
// NT=4 n-rows per thread amortize the hy read; masks staged in LDS as float,
// read back as one broadcast float4 per m.
// grid = 512 (b=2 x ntile=128 x ms=2), block = 256 (thread = h)
// ---------------------------------------------------------------------------
__global__ __launch_bounds__(256) void k_main(
    const float* __restrict__ hx, const float* __restrict__ hy,
    const int* __restrict__ mask, float* __restrict__ Spart)
{
    __shared__ float mf[256][4];          // [m_local][row]
    int blk   = blockIdx.x;
    int ms    = blk & 1;
    int ntile = (blk >> 1) & 127;
    int b     = blk >> 8;
    int n0    = ntile * 4;
    int t     = threadIdx.x;              // h

    const int* mrow = mask + (b * NN + n0) * MM + ms * 256;
#pragma unroll
    for (int i = 0; i < 4; ++i)
        mf[t][i] = (float)mrow[i * MM + t];
    __syncthreads();

    float hxv[4], acc[4] = {0.f, 0.f, 0.f, 0.f};
#pragma unroll
    for (int i = 0; i < 4; ++i)
        hxv[i] = hx[(b * NN + n0 + i) * HH + t];

    const float* hyp = hy + (b * MM + ms * 256) * HH + t;
#pragma unroll 4
    for (int m = 0; m < 256; ++m) {
        float hyv = hyp[m * HH];                       // coalesced, L2 hit
        float4 m4 = *(const float4*)&mf[m][0];         // LDS broadcast
        float t0 = fmaxf(hxv[0] + hyv, 0.f);
        float t1 = fmaxf(hxv[1] + hyv, 0.f);
        float t2 = fmaxf(hxv[2] + hyv, 0.f);
        float t3 = fmaxf(hxv[3] + hyv, 0.f);
        acc[0] = fmaf(t0, m4.x, acc[0]);
        acc[1] = fmaf(t1, m4.y, acc[1]);
        acc[2] = fmaf(t2, m4.z, acc[2]);
        acc[3] = fmaf(t3, m4.w, acc[3]);
    }
    float* sp = Spart + (size_t)ms * (BB * NN * HH) + (b * NN + n0) * HH + t;
#pragma unroll
    for (int i = 0; i < 4; ++i) sp[i * HH] = acc[i];
}

// ---------------------------------------------------------------------------
// Kernel C: per 4-row tile:
//   S = S0+S1; cnt = sum(mask); Zpre = X + S@W2 + cnt*b2; LN0;
//   u = relu(zn@Wf1+bf1); Z2 = zn + u@Wf2 + bf2; LN1 -> out
// Each weight element is read exactly once per block (split-k over h-halves).
// grid = 256 (b=2 x 128 tiles), block = 256
// ---------------------------------------------------------------------------
__global__ __launch_bounds__(256) void k_epi(
    const float* __restrict__ X, const int* __restrict__ mask,
    const float* __restrict__ Spart,
    const float* __restrict__ W2, const float* __restrict__ b2,
    const float* __restrict__ Wf1, const float* __restrict__ bf1,
    const float* __restrict__ Wf2, const float* __restrict__ bf2,
    const float* __restrict__ g0, const float* __restrict__ be0,
    const float* __restrict__ g1, const float* __restrict__ be1,
    float* __restrict__ out)
{
    __shared__ float sS[4][HH];
    __shared__ float szp[4][DD];
    __shared__ float sz[4][DD];
    __shared__ float su[4][HH];
    __shared__ float spart[2][4][DD];
    __shared__ float scnt[4];

    int blk = blockIdx.x;
    int b   = blk >> 7;
    int n0  = (blk & 127) * 4;
    int t   = threadIdx.x;
    int wave = t >> 6, lane = t & 63;

    // S = S0 + S1 (combine m-split partials)
#pragma unroll
    for (int i = 0; i < 4; ++i)
        sS[i][t] = Spart[(b * NN + n0 + i) * HH + t]
                 + Spart[(size_t)(BB * NN * HH) + (b * NN + n0 + i) * HH + t];

    // mask count per row (wave w handles row w)
    {
        const int* mrow = mask + (b * NN + n0 + wave) * MM;
        int c = 0;
#pragma unroll
        for (int k = 0; k < 8; ++k) c += mrow[lane + k * 64];
#pragma unroll
        for (int off = 32; off; off >>= 1) c += __shfl_down(c, off);
        if (lane == 0) scnt[wave] = (float)c;
    }
    __syncthreads();

    // Zpre = X + S@W2 + cnt*b2   (split-k: half = h-range)
    {
        int d = t & 127, half = t >> 7;
        float a0 = 0, a1 = 0, a2 = 0, a3 = 0;
        int hbase = half * 128;
        for (int h = 0; h < 128; ++h) {
            float w = W2[(hbase + h) * DD + d];        // each element once/block
            a0 = fmaf(sS[0][hbase + h], w, a0);
            a1 = fmaf(sS[1][hbase + h], w, a1);
            a2 = fmaf(sS[2][hbase + h], w, a2);
            a3 = fmaf(sS[3][hbase + h], w, a3);
        }
        spart[half][0][d] = a0; spart[half][1][d] = a1;
        spart[half][2][d] = a2; spart[half][3][d] = a3;
    }
    __syncthreads();
#pragma unroll
    for (int k = 0; k < 2; ++k) {
        int o = t + k * 256, i = o >> 7, d = o & 127;
        szp[i][d] = spart[0][i][d] + spart[1][i][d]
                  + X[(b * NN + n0 + i) * DD + d] + scnt[i] * b2[d];
    }
    __syncthreads();

    // LN0 (wave per row)
    {
        float v0 = szp[wave][lane], v1 = szp[wave][lane + 64];
        float s = v0 + v1, q = v0 * v0 + v1 * v1;
#pragma unroll
        for (int off = 32; off; off >>= 1) { s += __shfl_down(s, off); q += __shfl_down(q, off); }
        s = __shfl(s, 0); q = __shfl(q, 0);
        float mu   = s * (1.0f / 128.0f);
        float var  = q * (1.0f / 128.0f) - mu * mu;
        float rstd = rsqrtf(var + 1e-5f);
        sz[wave][lane]      = (v0 - mu) * rstd * g0[lane]      + be0[lane];
        sz[wave][lane + 64] = (v1 - mu) * rstd * g0[lane + 64] + be0[lane + 64];
    }
    __syncthreads();

    // u = relu(zn @ Wf1 + bf1)   (thread = h, 4 rows)
    {
        float bias = bf1[t];
        float a0 = bias, a1 = bias, a2 = bias, a3 = bias;
        for (int d = 0; d < DD; ++d) {
            float w = Wf1[d * HH + t];
            a0 = fmaf(sz[0][d], w, a0);
            a1 = fmaf(sz[1][d], w, a1);
            a2 = fmaf(sz[2][d], w, a2);
            a3 = fmaf(sz[3][d], w, a3);
        }
        su[0][t] = fmaxf(a0, 0.f);
        su[1][t] = fmaxf(a1, 0.f);
        su[2][t] = fmaxf(a2, 0.f);
        su[3][t] = fmaxf(a3, 0.f);
    }
    __syncthreads();

    // v = u @ Wf2; Z2 = zn + v + bf2
    {
        int d = t & 127, half = t >> 7;
        float a0 = 0, a1 = 0, a2 = 0, a3 = 0;
        int hbase = half * 128;
        for (int h = 0; h < 128; ++h) {
            float w = Wf2[(hbase + h) * DD + d];
            a0 = fmaf(su[0][hbase + h], w, a0);
            a1 = fmaf(su[1][hbase + h], w, a1);
            a2 = fmaf(su[2][hbase + h], w, a2);
            a3 = fmaf(su[3][hbase + h], w, a3);
        }
        spart[half][0][d] = a0; spart[half][1][d] = a1;
        spart[half][2][d] = a2; spart[half][3][d] = a3;
    }
    __syncthreads();
#pragma unroll
    for (int k = 0; k < 2; ++k) {
        int o = t + k * 256, i = o >> 7, d = o & 127;
        szp[i][d] = sz[i][d] + spart[0][i][d] + spart[1][i][d] + bf2[d];
    }
    __syncthreads();

    // LN1 + store
    {
        float v0 = szp[wave][lane], v1 = szp[wave][lane + 64];
        float s = v0 + v1, q = v0 * v0 + v1 * v1;
#pragma unroll
        for (int off = 32; off; off >>= 1) { s += __shfl_down(s, off); q += __shfl_down(q, off); }
        s = __shfl(s, 0); q = __shfl(q, 0);
        float mu   = s * (1.0f / 128.0f);
        float var  = q * (1.0f / 128.0f) - mu * mu;
        float rstd = rsqrtf(var + 1e-5f);
        int row = (b * NN + n0 + wave) * DD;
        out[row + lane]      = (v0 - mu) * rstd * g1[lane]      + be1[lane];
        out[row + lane + 64] = (v1 - mu) * rstd * g1[lane + 64] + be1[lane + 64];
    }
}

// ---------------------------------------------------------------------------
extern "C" void kernel_launch(void* const* d_in, const int* in_sizes, int n_in,
                              void* d_out, int out_size, void* d_ws, size_t ws_size,
                              hipStream_t stream)
{
    const float* X    = (const float*)d_in[0];
    const float* Y    = (const float*)d_in[1];
    const int*   mask = (const int*)d_in[2];
    const float* W1y  = (const float*)d_in[3];
    const float* W1x  = (const float*)d_in[4];
    const float* b1   = (const float*)d_in[5];
    const float* W2   = (const float*)d_in[6];
    const float* b2   = (const float*)d_in[7];
    const float* Wf1  = (const float*)d_in[8];
    const float* bf1  = (const float*)d_in[9];
    const float* Wf2  = (const float*)d_in[10];
    const float* bf2  = (const float*)d_in[11];
    const float* g0   = (const float*)d_in[12];
    const float* be0  = (const float*)d_in[13];
    const float* g1   = (const float*)d_in[14];
    const float* be1  = (const float*)d_in[15];
    float* out = (float*)d_out;

    // workspace layout (floats): hx[2*512*256] | hy[2*512*256] | Spart[2][2*512*256]
    float* ws = (float*)d_ws;
    float* hx = ws;
    float* hy = ws + BB * NN * HH;
    float* Sp = ws + 2 * BB * NN * HH;   // 2 m-split partials, 2 MB

    k_inproj<<<256, 256, 0, stream>>>(X, Y, W1x, W1y, b1, hx, hy);
    k_main  <<<512, 256, 0, stream>>>(hx, hy, mask, Sp);
    k_epi   <<<256, 256, 0, stream>>>(X, mask, Sp, W2, b2, Wf1, bf1, Wf2, bf2,
                                      g0, be0, g1, be1, out);
}

// Round 3
// 117.172 us; speedup vs baseline: 1.1555x; 1.1555x over previous
//
#include <hip/hip_runtime.h>

#define BB 2
#define NN 512
#define MM 512
#define DD 128
#define HH 256

// ---------------------------------------------------------------------------
// Kernel A: hx[b,n,h] = X[b,n,:]@W1x[:,h] + b1[h]   (b1 folded into hx)
//           hy[b,m,h] = Y[b,m,:]@W1y[:,h]
// 4-row register tile; grid = 512 (256 X-tiles + 256 Y-tiles) -> 2 blocks/CU
// block = 256 (thread = h). Unrolled so many W loads are in flight.
// ---------------------------------------------------------------------------
__global__ __launch_bounds__(256) void k_inproj(
    const float* __restrict__ X, const float* __restrict__ Y,
    const float* __restrict__ W1x, const float* __restrict__ W1y,
    const float* __restrict__ b1,
    float* __restrict__ hx, float* __restrict__ hy)
{
    __shared__ float sr[DD][4];   // transposed row tile for float4 broadcast
    int blk = blockIdx.x;
    bool isX = blk < 256;
    const float* src = isX ? X : Y;
    const float* W   = isX ? W1x : W1y;
    float* dst       = isX ? hx : hy;
    int row0 = (isX ? blk : blk - 256) * 4;
    int t = threadIdx.x;

#pragma unroll
    for (int k = 0; k < 2; ++k) {
        int idx = t + k * 256;             // 0..511 over (r,d), d fastest
        int r = idx >> 7, d = idx & 127;
        sr[d][r] = src[(row0 + r) * DD + d];
    }
    __syncthreads();

    float bias = isX ? b1[t] : 0.0f;
    float a0 = bias, a1 = bias, a2 = bias, a3 = bias;

#pragma unroll 16
    for (int d = 0; d < DD; ++d) {
        float w = W[d * HH + t];           // coalesced, L2-resident
        float4 a = *(const float4*)&sr[d][0];
        a0 = fmaf(a.x, w, a0);
        a1 = fmaf(a.y, w, a1);
        a2 = fmaf(a.z, w, a2);
        a3 = fmaf(a.w, w, a3);
    }
    dst[(row0 + 0) * HH + t] = a0;
    dst[(row0 + 1) * HH + t] = a1;
    dst[(row0 + 2) * HH + t] = a2;
    dst[(row0 + 3) * HH + t] = a3;
}

// ---------------------------------------------------------------------------
// Kernel B: Spart[ms][b,n,h] = sum_{m in quarter ms} mask[b,n,m]*relu(hx+hy)
// NT=4 n-rows per thread amortize the hy read; masks staged in LDS as float,
// read back as one broadcast float4 per m.
// grid = 1024 (b=2 x ntile=128 x ms=4) -> 4 waves/SIMD, block = 256 (thread=h)
// ---------------------------------------------------------------------------
__global__ __launch_bounds__(256) void k_main(
    const float* __restrict__ hx, const float* __restrict__ hy,
    const int* __restrict__ mask, float* __restrict__ Spart)
{
    __shared__ float mf[128][4];          // [m_local][row]
    int blk   = blockIdx.x;
    int ms    = blk & 3;
    int ntile = (blk >> 2) & 127;
    int b     = blk >> 9;
    int n0    = ntile * 4;
    int t     = threadIdx.x;              // h

    if (t < 128) {
        const int* mrow = mask + (b * NN + n0) * MM + ms * 128 + t;
#pragma unroll
        for (int i = 0; i < 4; ++i)
            mf[t][i] = (float)mrow[i * MM];
    }
    __syncthreads();

    float hxv[4], acc[4] = {0.f, 0.f, 0.f, 0.f};
#pragma unroll
    for (int i = 0; i < 4; ++i)
        hxv[i] = hx[(b * NN + n0 + i) * HH + t];

    const float* hyp = hy + (b * MM + ms * 128) * HH + t;
#pragma unroll 8
    for (int m = 0; m < 128; ++m) {
        float hyv = hyp[m * HH];                       // coalesced, L2 hit
        float4 m4 = *(const float4*)&mf[m][0];         // LDS broadcast
        float t0 = fmaxf(hxv[0] + hyv, 0.f);
        float t1 = fmaxf(hxv[1] + hyv, 0.f);
        float t2 = fmaxf(hxv[2] + hyv, 0.f);
        float t3 = fmaxf(hxv[3] + hyv, 0.f);
        acc[0] = fmaf(t0, m4.x, acc[0]);
        acc[1] = fmaf(t1, m4.y, acc[1]);
        acc[2] = fmaf(t2, m4.z, acc[2]);
        acc[3] = fmaf(t3, m4.w, acc[3]);
    }
    float* sp = Spart + (size_t)ms * (BB * NN * HH) + (b * NN + n0) * HH + t;
#pragma unroll
    for (int i = 0; i < 4; ++i) sp[i * HH] = acc[i];
}

// ---------------------------------------------------------------------------
// Kernel C: per 4-row tile:
//   S = sum of 4 Spart; cnt = sum(mask); Zpre = X + S@W2 + cnt*b2; LN0;
//   u = relu(zn@Wf1+bf1); Z2 = zn + u@Wf2 + bf2; LN1 -> out
// block = 512 threads (8 waves): H->D GEMMs split 4-way over h (64 iters),
// D->H GEMM split 2-way over d. grid = 256 blocks -> 2 waves/SIMD TLP
// plus 4-way shorter loops for ILP.
// ---------------------------------------------------------------------------
__global__ __launch_bounds__(512) void k_epi(
    const float* __restrict__ X, const int* __restrict__ mask,
    const float* __restrict__ Spart,
    const float* __restrict__ W2, const float* __restrict__ b2,
    const float* __restrict__ Wf1, const float* __restrict__ bf1,
    const float* __restrict__ Wf2, const float* __restrict__ bf2,
    const float* __restrict__ g0, const float* __restrict__ be0,
    const float* __restrict__ g1, const float* __restrict__ be1,
    float* __restrict__ out)
{
    __shared__ float sS[4][HH];        // 4 KB
    __shared__ float szp[4][DD];       // 2 KB
    __shared__ float sz[4][DD];        // 2 KB
    __shared__ float su[4][HH];        // 4 KB
    __shared__ float scratch[2048];    // 8 KB, reused between phases
    __shared__ float scnt[4];

    int blk = blockIdx.x;
    int b   = blk >> 7;
    int n0  = (blk & 127) * 4;
    int t   = threadIdx.x;
    int wave = t >> 6, lane = t & 63;

    // S = sum of the 4 m-split partials: 1024 values, 2 per thread, 8 loads
#pragma unroll
    for (int k = 0; k < 2; ++k) {
        int idx = t + k * 512;             // (r,h), h fastest
        int r = idx >> 8, h = idx & 255;
        size_t base = (size_t)(b * NN + n0 + r) * HH + h;
        sS[r][h] = Spart[base]
                 + Spart[base + (size_t)1 * BB * NN * HH]
                 + Spart[base + (size_t)2 * BB * NN * HH]
                 + Spart[base + (size_t)3 * BB * NN * HH];
    }

    // mask count per row (wave w<4 handles row w)
    if (wave < 4) {
        const int* mrow = mask + (b * NN + n0 + wave) * MM;
        int c = 0;
#pragma unroll
        for (int k = 0; k < 8; ++k) c += mrow[lane + k * 64];
#pragma unroll
        for (int off = 32; off; off >>= 1) c += __shfl_down(c, off);
        if (lane == 0) scnt[wave] = (float)c;
    }
    __syncthreads();

    // Zpre = X + S@W2 + cnt*b2   (split-k: quarter q of h-range, 64 iters)
    {
        int d = t & 127, q = t >> 7;       // q in 0..3
        float a0 = 0, a1 = 0, a2 = 0, a3 = 0;
        int hbase = q * 64;
#pragma unroll 8
        for (int h = 0; h < 64; ++h) {
            float w = W2[(hbase + h) * DD + d];
            a0 = fmaf(sS[0][hbase + h], w, a0);
            a1 = fmaf(sS[1][hbase + h], w, a1);
            a2 = fmaf(sS[2][hbase + h], w, a2);
            a3 = fmaf(sS[3][hbase + h], w, a3);
        }
        float* sp = scratch + (q * 4) * DD + d;   // [q][r][d]
        sp[0 * DD] = a0; sp[1 * DD] = a1; sp[2 * DD] = a2; sp[3 * DD] = a3;
    }
    __syncthreads();
    {
        int r = t >> 7, d = t & 127;       // 512 threads = 4 rows x 128 d
        szp[r][d] = scratch[(0 * 4 + r) * DD + d] + scratch[(1 * 4 + r) * DD + d]
                  + scratch[(2 * 4 + r) * DD + d] + scratch[(3 * 4 + r) * DD + d]
                  + X[(b * NN + n0 + r) * DD + d] + scnt[r] * b2[d];
    }
    __syncthreads();

    // LN0 (wave w<4 -> row w)
    if (wave < 4) {
        float v0 = szp[wave][lane], v1 = szp[wave][lane + 64];
        float s = v0 + v1, q = v0 * v0 + v1 * v1;
#pragma unroll
        for (int off = 32; off; off >>= 1) { s += __shfl_down(s, off); q += __shfl_down(q, off); }
        s = __shfl(s, 0); q = __shfl(q, 0);
        float mu   = s * (1.0f / 128.0f);
        float var  = q * (1.0f / 128.0f) - mu * mu;
        float rstd = rsqrtf(var + 1e-5f);
        sz[wave][lane]      = (v0 - mu) * rstd * g0[lane]      + be0[lane];
        sz[wave][lane + 64] = (v1 - mu) * rstd * g0[lane + 64] + be0[lane + 64];
    }
    __syncthreads();

    // u = relu(zn @ Wf1 + bf1)   (h = t&255, d-half = t>>8, 64 iters)
    {
        int h = t & 255, dh = t >> 8;      // dh in 0..1
        float a0 = 0, a1 = 0, a2 = 0, a3 = 0;
        int dbase = dh * 64;
#pragma unroll 8
        for (int d = 0; d < 64; ++d) {
            float w = Wf1[(dbase + d) * HH + h];
            a0 = fmaf(sz[0][dbase + d], w, a0);
            a1 = fmaf(sz[1][dbase + d], w, a1);
            a2 = fmaf(sz[2][dbase + d], w, a2);
            a3 = fmaf(sz[3][dbase + d], w, a3);
        }
        float* sp = scratch + (dh * 4) * HH + h;  // [dh][r][h]
        sp[0 * HH] = a0; sp[1 * HH] = a1; sp[2 * HH] = a2; sp[3 * HH] = a3;
    }
    __syncthreads();
#pragma unroll
    for (int k = 0; k < 2; ++k) {
        int idx = t + k * 512;             // (r,h)
        int r = idx >> 8, h = idx & 255;
        su[r][h] = fmaxf(scratch[(0 * 4 + r) * HH + h]
                       + scratch[(1 * 4 + r) * HH + h] + bf1[h], 0.f);
    }
    __syncthreads();

    // v = u @ Wf2; Z2 = zn + v + bf2   (quarter split over h again)
    {
        int d = t & 127, q = t >> 7;
        float a0 = 0, a1 = 0, a2 = 0, a3 = 0;
        int hbase = q * 64;
#pragma unroll 8
        for (int h = 0; h < 64; ++h) {
            float w = Wf2[(hbase + h) * DD + d];
            a0 = fmaf(su[0][hbase + h], w, a0);
            a1 = fmaf(su[1][hbase + h], w, a1);
            a2 = fmaf(su[2][hbase + h], w, a2);
            a3 = fmaf(su[3][hbase + h], w, a3);
        }
        float* sp = scratch + (q * 4) * DD + d;
        sp[0 * DD] = a0; sp[1 * DD] = a1; sp[2 * DD] = a2; sp[3 * DD] = a3;
    }
    __syncthreads();
    {
        int r = t >> 7, d = t & 127;
        szp[r][d] = sz[r][d] + bf2[d]
                  + scratch[(0 * 4 + r) * DD + d] + scratch[(1 * 4 + r) * DD + d]
                  + scratch[(2 * 4 + r) * DD + d] + scratch[(3 * 4 + r) * DD + d];
    }
    __syncthreads();

    // LN1 + store
    if (wave < 4) {
        float v0 = szp[wave][lane], v1 = szp[wave][lane + 64];
        float s = v0 + v1, q = v0 * v0 + v1 * v1;
#pragma unroll
        for (int off = 32; off; off >>= 1) { s += __shfl_down(s, off); q += __shfl_down(q, off); }
        s = __shfl(s, 0); q = __shfl(q, 0);
        float mu   = s * (1.0f / 128.0f);
        float var  = q * (1.0f / 128.0f) - mu * mu;
        float rstd = rsqrtf(var + 1e-5f);
        int row = (b * NN + n0 + wave) * DD;
        out[row + lane]      = (v0 - mu) * rstd * g1[lane]      + be1[lane];
        out[row + lane + 64] = (v1 - mu) * rstd * g1[lane + 64] + be1[lane + 64];
    }
}

// ---------------------------------------------------------------------------
extern "C" void kernel_launch(void* const* d_in, const int* in_sizes, int n_in,
                              void* d_out, int out_size, void* d_ws, size_t ws_size,
                              hipStream_t stream)
{
    const float* X    = (const float*)d_in[0];
    const float* Y    = (const float*)d_in[1];
    const int*   mask = (const int*)d_in[2];
    const float* W1y  = (const float*)d_in[3];
    const float* W1x  = (const float*)d_in[4];
    const float* b1   = (const float*)d_in[5];
    const float* W2   = (const float*)d_in[6];
    const float* b2   = (const float*)d_in[7];
    const float* Wf1  = (const float*)d_in[8];
    const float* bf1  = (const float*)d_in[9];
    const float* Wf2  = (const float*)d_in[10];
    const float* bf2  = (const float*)d_in[11];
    const float* g0   = (const float*)d_in[12];
    const float* be0  = (const float*)d_in[13];
    const float* g1   = (const float*)d_in[14];
    const float* be1  = (const float*)d_in[15];
    float* out = (float*)d_out;

    // workspace (floats): hx[2*512*256] | hy[2*512*256] | Spart[4][2*512*256]
    float* ws = (float*)d_ws;
    float* hx = ws;
    float* hy = ws + BB * NN * HH;
    float* Sp = ws + 2 * BB * NN * HH;   // 4 m-split partials, 4 MB

    k_inproj<<<512, 256, 0, stream>>>(X, Y, W1x, W1y, b1, hx, hy);
    k_main  <<<1024, 256, 0, stream>>>(hx, hy, mask, Sp);
    k_epi   <<<256, 512, 0, stream>>>(X, mask, Sp, W2, b2, Wf1, bf1, Wf2, bf2,
                                      g0, be0, g1, be1, out);
}